// Round 1
// baseline (461.680 us; speedup 1.0000x reference)
//
#include <hip/hip_runtime.h>
#include <hip/hip_bf16.h>

// GIN: 3x [agg = segment_sum(h[src], dst); r = h + agg; h = relu(r@Wa+ba)@Wb+bb]
// then mean over nodes @ Wout + bout -> [1,16]
//
// Strategy: device-side CSR build (histogram + scan + fill) each call, then
// wave-per-node gather aggregation (no fp32 atomics), then LDS-tiled fused
// MLP (both matmuls in one kernel), then 2-stage mean-pool + tiny final GEMV.

#define NNODES 50000
#define NEDGES 800000
#define DDIM   64
#define DOUT   16

// ---------------- CSR build ----------------

__global__ void zero_int_kernel(int* p, int n) {
    int i = blockIdx.x * 256 + threadIdx.x;
    if (i < n) p[i] = 0;
}

__global__ void hist_kernel(const int* __restrict__ dst, int* __restrict__ deg, int n) {
    int i = blockIdx.x * 256 + threadIdx.x;
    if (i < n) atomicAdd(&deg[dst[i]], 1);
}

// inclusive scan of 256-chunks; chunk totals to bsums
__global__ __launch_bounds__(256) void scan_chunk_kernel(const int* __restrict__ deg,
                                                         int* __restrict__ incl,
                                                         int* __restrict__ bsums, int n) {
    __shared__ int s[256];
    int i = blockIdx.x * 256 + threadIdx.x;
    int v = (i < n) ? deg[i] : 0;
    s[threadIdx.x] = v;
    __syncthreads();
    for (int off = 1; off < 256; off <<= 1) {
        int add = (threadIdx.x >= off) ? s[threadIdx.x - off] : 0;
        __syncthreads();
        s[threadIdx.x] += add;
        __syncthreads();
    }
    if (i < n) incl[i] = s[threadIdx.x];
    if (threadIdx.x == 255) bsums[blockIdx.x] = s[255];
}

// exclusive scan of block sums (single block, nb <= 256)
__global__ __launch_bounds__(256) void scan_bsums_kernel(const int* __restrict__ bsums,
                                                         int* __restrict__ boff, int nb) {
    __shared__ int s[256];
    int v = (threadIdx.x < nb) ? bsums[threadIdx.x] : 0;
    s[threadIdx.x] = v;
    __syncthreads();
    for (int off = 1; off < 256; off <<= 1) {
        int add = (threadIdx.x >= off) ? s[threadIdx.x - off] : 0;
        __syncthreads();
        s[threadIdx.x] += add;
        __syncthreads();
    }
    boff[threadIdx.x] = s[threadIdx.x] - v;  // exclusive
}

__global__ void finalize_rowptr_kernel(const int* __restrict__ deg,
                                       const int* __restrict__ incl,
                                       const int* __restrict__ boff,
                                       int* __restrict__ rowptr,
                                       int* __restrict__ fillp, int n) {
    int i = blockIdx.x * 256 + threadIdx.x;
    if (i < n) {
        int excl = incl[i] - deg[i] + boff[i >> 8];
        rowptr[i] = excl;
        fillp[i] = excl;
        if (i == n - 1) rowptr[n] = excl + deg[i];
    }
}

__global__ void fill_kernel(const int* __restrict__ src, const int* __restrict__ dst,
                            int* __restrict__ fillp, int* __restrict__ csr, int n) {
    int i = blockIdx.x * 256 + threadIdx.x;
    if (i < n) {
        int p = atomicAdd(&fillp[dst[i]], 1);
        csr[p] = src[i];
    }
}

// ---------------- aggregation: r[n] = h[n] + sum_{e in in(n)} h[src[e]] ----------------

__global__ __launch_bounds__(256) void agg_kernel(const float* __restrict__ hin,
                                                  const int* __restrict__ rowptr,
                                                  const int* __restrict__ csr,
                                                  float* __restrict__ r, int n) {
    int node = (blockIdx.x * 256 + threadIdx.x) >> 6;
    int lane = threadIdx.x & 63;
    if (node >= n) return;
    int beg = rowptr[node];
    int end = rowptr[node + 1];
    float acc = hin[(size_t)node * DDIM + lane];
    int e = beg;
    for (; e + 1 < end; e += 2) {
        int s0 = csr[e];
        int s1 = csr[e + 1];
        float v0 = hin[(size_t)s0 * DDIM + lane];
        float v1 = hin[(size_t)s1 * DDIM + lane];
        acc += v0;
        acc += v1;
    }
    if (e < end) acc += hin[(size_t)csr[e] * DDIM + lane];
    r[(size_t)node * DDIM + lane] = acc;
}

// ---------------- fused MLP: out = relu(r@Wa+ba)@Wb+bb ----------------
// 64-node tile per block, 256 threads, 4x4 register micro-tile per thread.

__global__ __launch_bounds__(256) void mlp_kernel(const float* __restrict__ r,
                                                  const float* __restrict__ Wa,
                                                  const float* __restrict__ ba,
                                                  const float* __restrict__ Wb,
                                                  const float* __restrict__ bb,
                                                  float* __restrict__ out, int n) {
    __shared__ float sA[64][64];   // Wa[k][j]
    __shared__ float sB[64][64];   // Wb[k][j]
    __shared__ float sR[64][65];   // r tile [node][k], padded
    __shared__ float sH[64][65];   // hidden tile, padded
    __shared__ float sba[64], sbb[64];

    int t = threadIdx.x;
    for (int i = t; i < 1024; i += 256) {
        ((float4*)sA)[i] = ((const float4*)Wa)[i];
        ((float4*)sB)[i] = ((const float4*)Wb)[i];
    }
    if (t < 64) { sba[t] = ba[t]; sbb[t] = bb[t]; }

    int node0 = blockIdx.x * 64;
    for (int i = t; i < 1024; i += 256) {
        int row = i >> 4;       // 0..63
        int c4  = i & 15;       // float4 index within row
        int gr = node0 + row;
        float4 v = make_float4(0.f, 0.f, 0.f, 0.f);
        if (gr < n) v = ((const float4*)(r + (size_t)gr * DDIM))[c4];
        sR[row][c4 * 4 + 0] = v.x;
        sR[row][c4 * 4 + 1] = v.y;
        sR[row][c4 * 4 + 2] = v.z;
        sR[row][c4 * 4 + 3] = v.w;
    }
    __syncthreads();

    int tx = t & 15;            // output-col group: j0 = tx*4
    int ty = t >> 4;            // node-row group:  i0 = ty*4
    int j0 = tx * 4, i0 = ty * 4;

    float acc[4][4];
#pragma unroll
    for (int a = 0; a < 4; a++)
#pragma unroll
        for (int b = 0; b < 4; b++) acc[a][b] = 0.f;

#pragma unroll 8
    for (int k = 0; k < 64; k++) {
        float a0 = sR[i0 + 0][k];
        float a1 = sR[i0 + 1][k];
        float a2 = sR[i0 + 2][k];
        float a3 = sR[i0 + 3][k];
        float4 bv = *(const float4*)&sA[k][j0];
        acc[0][0] += a0 * bv.x; acc[0][1] += a0 * bv.y; acc[0][2] += a0 * bv.z; acc[0][3] += a0 * bv.w;
        acc[1][0] += a1 * bv.x; acc[1][1] += a1 * bv.y; acc[1][2] += a1 * bv.z; acc[1][3] += a1 * bv.w;
        acc[2][0] += a2 * bv.x; acc[2][1] += a2 * bv.y; acc[2][2] += a2 * bv.z; acc[2][3] += a2 * bv.w;
        acc[3][0] += a3 * bv.x; acc[3][1] += a3 * bv.y; acc[3][2] += a3 * bv.z; acc[3][3] += a3 * bv.w;
    }

#pragma unroll
    for (int a = 0; a < 4; a++)
#pragma unroll
        for (int b = 0; b < 4; b++)
            sH[i0 + a][j0 + b] = fmaxf(acc[a][b] + sba[j0 + b], 0.f);
    __syncthreads();

#pragma unroll
    for (int a = 0; a < 4; a++)
#pragma unroll
        for (int b = 0; b < 4; b++) acc[a][b] = 0.f;

#pragma unroll 8
    for (int k = 0; k < 64; k++) {
        float a0 = sH[i0 + 0][k];
        float a1 = sH[i0 + 1][k];
        float a2 = sH[i0 + 2][k];
        float a3 = sH[i0 + 3][k];
        float4 bv = *(const float4*)&sB[k][j0];
        acc[0][0] += a0 * bv.x; acc[0][1] += a0 * bv.y; acc[0][2] += a0 * bv.z; acc[0][3] += a0 * bv.w;
        acc[1][0] += a1 * bv.x; acc[1][1] += a1 * bv.y; acc[1][2] += a1 * bv.z; acc[1][3] += a1 * bv.w;
        acc[2][0] += a2 * bv.x; acc[2][1] += a2 * bv.y; acc[2][2] += a2 * bv.z; acc[2][3] += a2 * bv.w;
        acc[3][0] += a3 * bv.x; acc[3][1] += a3 * bv.y; acc[3][2] += a3 * bv.z; acc[3][3] += a3 * bv.w;
    }

#pragma unroll
    for (int a = 0; a < 4; a++) {
        int gr = node0 + i0 + a;
        if (gr < n) {
            float4 o;
            o.x = acc[a][0] + sbb[j0 + 0];
            o.y = acc[a][1] + sbb[j0 + 1];
            o.z = acc[a][2] + sbb[j0 + 2];
            o.w = acc[a][3] + sbb[j0 + 3];
            ((float4*)(out + (size_t)gr * DDIM))[tx] = o;
        }
    }
}

// ---------------- mean pool (2 stages) + final linear ----------------

__global__ __launch_bounds__(256) void colsum_part_kernel(const float* __restrict__ h,
                                                          float* __restrict__ part, int n) {
    __shared__ float red[4][64];
    int lane = threadIdx.x & 63;
    int w = threadIdx.x >> 6;
    int gw = blockIdx.x * 4 + w;
    int stride = gridDim.x * 4;
    float acc = 0.f;
    for (int i = gw; i < n; i += stride) acc += h[(size_t)i * DDIM + lane];
    red[w][lane] = acc;
    __syncthreads();
    if (w == 0)
        part[blockIdx.x * 64 + lane] = red[0][lane] + red[1][lane] + red[2][lane] + red[3][lane];
}

__global__ __launch_bounds__(64) void final_kernel(const float* __restrict__ part,
                                                   const float* __restrict__ Wout,
                                                   const float* __restrict__ bout,
                                                   float* __restrict__ out, int nparts) {
    __shared__ float cs[64];
    int t = threadIdx.x;  // 64 threads
    float s = 0.f;
    for (int b = 0; b < nparts; b++) s += part[b * 64 + t];
    cs[t] = s * (1.0f / (float)NNODES);
    __syncthreads();
    if (t < DOUT) {
        float o = bout[t];
        for (int d = 0; d < DDIM; d++) o += cs[d] * Wout[d * DOUT + t];
        out[t] = o;
    }
}

// ---------------- launch ----------------

extern "C" void kernel_launch(void* const* d_in, const int* in_sizes, int n_in,
                              void* d_out, int out_size, void* d_ws, size_t ws_size,
                              hipStream_t stream) {
    const float* features = (const float*)d_in[0];
    const int*   src      = (const int*)d_in[1];
    const int*   dst      = (const int*)d_in[2];
    const float* W0a = (const float*)d_in[3];  const float* b0a = (const float*)d_in[4];
    const float* W0b = (const float*)d_in[5];  const float* b0b = (const float*)d_in[6];
    const float* W1a = (const float*)d_in[7];  const float* b1a = (const float*)d_in[8];
    const float* W1b = (const float*)d_in[9];  const float* b1b = (const float*)d_in[10];
    const float* W2a = (const float*)d_in[11]; const float* b2a = (const float*)d_in[12];
    const float* W2b = (const float*)d_in[13]; const float* b2b = (const float*)d_in[14];
    const float* Wout = (const float*)d_in[15]; const float* bout = (const float*)d_in[16];
    float* out = (float*)d_out;

    // workspace layout (all offsets keep 16B alignment)
    int* deg    = (int*)d_ws;            // [50048]
    int* incl   = deg + 50048;           // [50048]
    int* rowptr = incl + 50048;          // [50064] (50001 used)
    int* fillp  = rowptr + 50064;        // [50048]
    int* bsums  = fillp + 50048;         // [256]
    int* boff   = bsums + 256;           // [256]
    int* csr    = boff + 256;            // [800000]
    float* bufR  = (float*)(csr + 800000);   // [3200000]
    float* bufH1 = bufR + 3200000;           // [3200000]
    float* bufH2 = bufH1 + 3200000;          // [3200000]
    float* part  = bufH2 + 3200000;          // [128*64]

    const int NB_N = (NNODES + 255) / 256;   // 196
    const int NB_E = (NEDGES + 255) / 256;   // 3125

    // CSR build
    zero_int_kernel<<<NB_N, 256, 0, stream>>>(deg, NNODES);
    hist_kernel<<<NB_E, 256, 0, stream>>>(dst, deg, NEDGES);
    scan_chunk_kernel<<<NB_N, 256, 0, stream>>>(deg, incl, bsums, NNODES);
    scan_bsums_kernel<<<1, 256, 0, stream>>>(bsums, boff, NB_N);
    finalize_rowptr_kernel<<<NB_N, 256, 0, stream>>>(deg, incl, boff, rowptr, fillp, NNODES);
    fill_kernel<<<NB_E, 256, 0, stream>>>(src, dst, fillp, csr, NEDGES);

    const int AGG_BLOCKS = (NNODES + 3) / 4;     // wave per node, 4 waves/block
    const int MLP_BLOCKS = (NNODES + 63) / 64;   // 782

    // layer 0
    agg_kernel<<<AGG_BLOCKS, 256, 0, stream>>>(features, rowptr, csr, bufR, NNODES);
    mlp_kernel<<<MLP_BLOCKS, 256, 0, stream>>>(bufR, W0a, b0a, W0b, b0b, bufH1, NNODES);
    // layer 1
    agg_kernel<<<AGG_BLOCKS, 256, 0, stream>>>(bufH1, rowptr, csr, bufR, NNODES);
    mlp_kernel<<<MLP_BLOCKS, 256, 0, stream>>>(bufR, W1a, b1a, W1b, b1b, bufH2, NNODES);
    // layer 2
    agg_kernel<<<AGG_BLOCKS, 256, 0, stream>>>(bufH2, rowptr, csr, bufR, NNODES);
    mlp_kernel<<<MLP_BLOCKS, 256, 0, stream>>>(bufR, W2a, b2a, W2b, b2b, bufH1, NNODES);

    // mean pool + final linear
    colsum_part_kernel<<<128, 256, 0, stream>>>(bufH1, part, NNODES);
    final_kernel<<<1, 64, 0, stream>>>(part, Wout, bout, out, 128);
}